// Round 1
// 214.381 us; speedup vs baseline: 1.0011x; 1.0011x over previous
//
#include <hip/hip_runtime.h>
#include <math.h>

#define NIMG 32
#define NB3  771             // 257 rings * 3 sums
#define PI_F 3.14159265358979323846f

// ---------------------------------------------------------------------------
__device__ __forceinline__ float2 cadd(float2 a, float2 b){ return make_float2(a.x+b.x, a.y+b.y); }
__device__ __forceinline__ float2 csub(float2 a, float2 b){ return make_float2(a.x-b.x, a.y-b.y); }
__device__ __forceinline__ float2 cmul(float2 a, float2 b){ return make_float2(a.x*b.x - a.y*b.y, a.x*b.y + a.y*b.x); }
__device__ __forceinline__ float2 cmul_mi(float2 a){ return make_float2(a.y, -a.x); }   // * (-i)
__device__ __forceinline__ float2 tw(const float2* T, int m){ return T[m + (m >> 3)]; }
__device__ __forceinline__ int   sw(int pos){ return pos + (pos >> 3); }     // LDS pad swizzle

// 8-point DFT (DIF, natural-order outputs), e^{-2pi i/8} convention
__device__ __forceinline__ void dft8(float2* x) {
    const float c = 0.70710678118654752f;
    float2 u0 = cadd(x[0], x[4]), u1 = cadd(x[1], x[5]);
    float2 u2 = cadd(x[2], x[6]), u3 = cadd(x[3], x[7]);
    float2 v0 = csub(x[0], x[4]);
    float2 d1 = csub(x[1], x[5]);
    float2 v1 = make_float2(c*(d1.x + d1.y), c*(d1.y - d1.x));
    float2 d2 = csub(x[2], x[6]);
    float2 v2 = make_float2(d2.y, -d2.x);
    float2 d3 = csub(x[3], x[7]);
    float2 v3 = make_float2(-c*(d3.x - d3.y), -c*(d3.x + d3.y));
    float2 e0 = cadd(u0,u2), e1 = cadd(u1,u3);
    float2 f0 = csub(u0,u2), f1 = cmul_mi(csub(u1,u3));
    float2 g0 = cadd(v0,v2), g1 = cadd(v1,v3);
    float2 h0 = csub(v0,v2), h1 = cmul_mi(csub(v1,v3));
    x[0] = cadd(e0,e1); x[4] = csub(e0,e1);
    x[2] = cadd(f0,f1); x[6] = csub(f0,f1);
    x[1] = cadd(g0,g1); x[5] = csub(g0,g1);
    x[3] = cadd(h0,h1); x[7] = csub(h0,h1);
}

// ---------------------------------------------------------------------------
// Per-wave 512-pt radix-8 DIF FFT, barrier-free (wave-private 576-slot LDS
// scratch; one wave's LDS ops execute in order). Thread J enters with
// X[q] = x[J + 64q], exits with X[k] = F(64k + r), r = 8*(J&7) + (J>>3).
// ---------------------------------------------------------------------------
__device__ __forceinline__ void wave_fft512(float2* X, float2* Sw,
                                            const float2* T, int J) {
    dft8(X);
#pragma unroll
    for (int k = 1; k < 8; ++k) X[k] = cmul(X[k], tw(T, J * k));
    const int jj = J + (J >> 3);
#pragma unroll
    for (int k = 0; k < 8; ++k) Sw[jj + 72*k] = X[k];

    const int j2 = J & 7;
    const int bb = 72 * (J >> 3) + j2;
#pragma unroll
    for (int q = 0; q < 8; ++q) X[q] = Sw[bb + 9*q];
    dft8(X);
#pragma unroll
    for (int k = 1; k < 8; ++k) X[k] = cmul(X[k], tw(T, 8 * j2 * k));
#pragma unroll
    for (int k = 0; k < 8; ++k) Sw[bb + 9*k] = X[k];

#pragma unroll
    for (int q = 0; q < 8; ++q) X[q] = Sw[9*J + q];
    dft8(X);
}

// ---------------------------------------------------------------------------
// Row pass (unchanged — control variable). Writes transposed Zt[kx][y].
// ---------------------------------------------------------------------------
__global__ __launch_bounds__(256, 6) void fft_rows_T(const float* __restrict__ xr,
                                                     const float* __restrict__ yr,
                                                     float2* __restrict__ Zt) {
    __shared__ float2 S[4 * 576];
    __shared__ float2 T[576];
    const int t = threadIdx.x, w = t >> 6, J = t & 63;
    const int im = blockIdx.x >> 6, grp = blockIdx.x & 63;

#pragma unroll
    for (int i = 0; i < 2; ++i) {
        const int m = t + 256 * i;
        float s, c;
        __sincosf(-2.0f * PI_F * (float)m / 512.0f, &s, &c);
        T[m + (m >> 3)] = make_float2(c, s);
    }

    const size_t b0 = ((size_t)(im * 512 + grp * 8 + w)) << 9;
    const size_t b1 = b0 + (4u << 9);
    float2 X0[8], X1[8];
#pragma unroll
    for (int q = 0; q < 8; ++q) {
        X0[q] = make_float2(xr[b0 + J + 64*q], yr[b0 + J + 64*q]);
        X1[q] = make_float2(xr[b1 + J + 64*q], yr[b1 + J + 64*q]);
    }
    __syncthreads();                       // T ready

    float2* Sw = S + w * 576;
    wave_fft512(X0, Sw, T, J);
    wave_fft512(X1, Sw, T, J);

    const int r = ((J & 7) << 3) | (J >> 3);

#pragma unroll
    for (int k = 0; k < 8; ++k) Sw[64*k + r] = X0[k];
    __syncthreads();
    float2 eA[4], eB[4];
#pragma unroll
    for (int j = 0; j < 4; ++j) { eA[j] = S[j*576 + t]; eB[j] = S[j*576 + t + 256]; }
    __syncthreads();

#pragma unroll
    for (int k = 0; k < 8; ++k) Sw[64*k + r] = X1[k];
    __syncthreads();

    const size_t zb = ((size_t)im << 18) + (grp << 3);
    {
        float4* o = (float4*)(Zt + zb + ((size_t)t << 9));
        float2 f0 = S[0*576 + t], f1 = S[1*576 + t];
        float2 f2 = S[2*576 + t], f3 = S[3*576 + t];
        o[0] = make_float4(eA[0].x, eA[0].y, eA[1].x, eA[1].y);
        o[1] = make_float4(eA[2].x, eA[2].y, eA[3].x, eA[3].y);
        o[2] = make_float4(f0.x, f0.y, f1.x, f1.y);
        o[3] = make_float4(f2.x, f2.y, f3.x, f3.y);
    }
    {
        float4* o = (float4*)(Zt + zb + ((size_t)(t + 256) << 9));
        float2 f0 = S[0*576 + t + 256], f1 = S[1*576 + t + 256];
        float2 f2 = S[2*576 + t + 256], f3 = S[3*576 + t + 256];
        o[0] = make_float4(eB[0].x, eB[0].y, eB[1].x, eB[1].y);
        o[1] = make_float4(eB[2].x, eB[2].y, eB[3].x, eB[3].y);
        o[2] = make_float4(f0.x, f0.y, f1.x, f1.y);
        o[3] = make_float4(f2.x, f2.y, f3.x, f3.y);
    }
}

// ---------------------------------------------------------------------------
// Fused column FFT + rings, v3: ONE 576-slot scratch region per wave.
// v2 kept two regions (A for col p, B for col 512-p) so the p>=1 ring phase
// could read A[ky] and B[512-ky] together -> 44 KiB LDS -> 3 blocks/CU ->
// occupancy 17.8%, VALUBusy 19% (latency-bound, rocprof r0).
// v3: park col A, pull the 8 needed mirror values A[sw(8J+i)] (contiguous,
// 16 VGPRs) into registers, then REUSE the same scratch for col B (wave-
// private LDS ops execute in order -> the saved reads complete before B's
// FFT overwrites them). p==0 (self-mirror cols 0 and 256) just processes
// col A's rings before FFT-ing col B — no extra registers.
// LDS: 18432(S) + 4608(T) + 3096(bins) ~= 26 KiB -> 6 blocks/CU = 24 waves/CU.
// ---------------------------------------------------------------------------
__global__ __launch_bounds__(256, 6) void fft_cols_rings(const float2* __restrict__ Zt,
                                                         float* __restrict__ sums,
                                                         int big) {
    __shared__ float2 S[4 * 576];      // 1 region per wave: 18,432 B
    __shared__ float2 T[576];          //  4,608 B
    __shared__ float  bins[258 * 3];   //  3,096 B
    const int t = threadIdx.x, w = t >> 6, J = t & 63;
    const int im = blockIdx.x >> 6, g = blockIdx.x & 63;
    const int p = 4 * g + w;

#pragma unroll
    for (int i = 0; i < 2; ++i) {
        const int m = t + 256 * i;
        float s, c;
        __sincosf(-2.0f * PI_F * (float)m / 512.0f, &s, &c);
        T[m + (m >> 3)] = make_float2(c, s);
    }
    for (int i = t; i < 258 * 3; i += 256) bins[i] = 0.0f;

    const int c0 = (p == 0) ? 0   : p;
    const int c1 = (p == 0) ? 256 : 512 - p;
    const float2* rp0 = Zt + ((size_t)im << 18) + ((size_t)c0 << 9);
    const float2* rp1 = Zt + ((size_t)im << 18) + ((size_t)c1 << 9);
    float2 X0[8], X1[8];
#pragma unroll
    for (int q = 0; q < 8; ++q) { X0[q] = rp0[J + 64*q]; X1[q] = rp1[J + 64*q]; }
    __syncthreads();                       // T ready, bins zeroed

    float2* A = S + w * 576;               // single wave-private region
    const int r  = ((J & 7) << 3) | (J >> 3);
    const int pk = r + (r >> 3);           // sw(64k + r) = 72k + pk

    const float scale = 1.0f / (512.0f * 512.0f);
    auto pix = [&](float2 zk, float2 zm, float& av, float& c1v, float& c2v) {
        float f1r = 0.5f * (zk.x + zm.x) * scale;
        float f1i = 0.5f * (zk.y - zm.y) * scale;
        float f2r = 0.5f * (zk.y + zm.y) * scale;
        float f2i = 0.5f * (zm.x - zk.x) * scale;
        av  = f1r * f2r + f1i * f2i;
        c1v = f1r * f1r + f1i * f1i;
        c2v = f2r * f2r + f2i * f2i;
    };
    auto flush = [&](int ring, float a, float b, float c) {
        if (ring >= 0 && ring <= 256) {
            unsafeAtomicAdd(&bins[ring*3+0], a);
            unsafeAtomicAdd(&bins[ring*3+1], b);
            unsafeAtomicAdd(&bins[ring*3+2], c);
        }
    };

    // ---- column A: FFT + park (natural order, swizzled)
    wave_fft512(X0, A, T, J);
#pragma unroll
    for (int k = 0; k < 8; ++k) A[72*k + pk] = X0[k];

    float2 asv[8];                         // p>=1: mirror values saved across B's FFT
    if (p == 0) {
        // col 0 is self-mirror: process its rings now, straight from A.
        int cur0 = -1;
        float a0 = 0, b0 = 0, c0v = 0;
#pragma unroll
        for (int i = 0; i < 8; ++i) {
            const int ky  = 8*J + i;
            const int kyp = (512 - ky) & 511;
            float2 zk = A[sw(ky)], zm = A[sw(kyp)];
            const float fk = (ky < 256) ? (float)ky : (float)(ky - 512);
            float av, cv, dv;
            pix(zk, zm, av, cv, dv);                       // col 0, fy = 0
            int rr = (int)rintf(fabsf(fk)); if (rr > 256) rr = 257;
            if (rr != cur0) { flush(cur0, a0, b0, c0v); cur0 = rr; a0 = av; b0 = cv; c0v = dv; }
            else            { a0 += av; b0 += cv; c0v += dv; }
        }
        flush(cur0, a0, b0, c0v);
    } else {
        // Save A[sw(8J+i)] = A[9J+i], i=0..7 (contiguous) before reuse.
#pragma unroll
        for (int i = 0; i < 8; ++i) asv[i] = A[9*J + i];
    }

    // ---- column B: FFT + park in the SAME region (in-wave order is safe:
    //      the asv/ring reads above were issued before these writes)
    wave_fft512(X1, A, T, J);
#pragma unroll
    for (int k = 0; k < 8; ++k) A[72*k + pk] = X1[k];

    if (p == 0) {
        // col 256 is self-mirror too (512-256 = 256): rings from A (= col 256).
        int cur1 = -1;
        float a1 = 0, b1 = 0, c1v = 0;
#pragma unroll
        for (int i = 0; i < 8; ++i) {
            const int ky  = 8*J + i;
            const int kyp = (512 - ky) & 511;
            float2 zk = A[sw(ky)], zm = A[sw(kyp)];
            const float fk = (ky < 256) ? (float)ky : (float)(ky - 512);
            float av, cv, dv;
            pix(zk, zm, av, cv, dv);                       // col 256, fy = 256
            int rr = (int)rintf(sqrtf(fk*fk + 65536.0f)); if (rr > 256) rr = 257;
            if (rr != cur1) { flush(cur1, a1, b1, c1v); cur1 = rr; a1 = av; b1 = cv; c1v = dv; }
            else            { a1 += av; b1 += cv; c1v += dv; }
        }
        flush(cur1, a1, b1, c1v);
    } else {
        const float fy2 = (float)p * (float)p;
        int curR = -1;
        float sA = 0, sB = 0, sC = 0;
#pragma unroll
        for (int i = 0; i < 8; ++i) {
            const int ky  = 8*J + i;
            const int kyp = (512 - ky) & 511;
            float2 zk = asv[i];              // P0[ky]            (saved from col A)
            float2 zm = A[sw(kyp)];          // P1[512-ky]        (col B, parked)
            float a1v, b1v, d1v, a2v, b2v, d2v;
            pix(zk, zm, a1v, b1v, d1v);      // pixel (p, ky),        partner (512-p, 512-ky)
            pix(zm, zk, a2v, b2v, d2v);      // pixel (512-p,512-ky), partner (p, ky)
            const float fk = (ky < 256) ? (float)ky : (float)(ky - 512);
            int rr = (int)rintf(sqrtf(fk*fk + fy2)); if (rr > 256) rr = 257;
            const float aa = a1v + a2v, bb = b1v + b2v, cc = d1v + d2v;
            if (rr != curR) { flush(curR, sA, sB, sC); curR = rr; sA = aa; sB = bb; sC = cc; }
            else            { sA += aa; sB += bb; sC += cc; }
        }
        flush(curR, sA, sB, sC);
    }
    __syncthreads();

    if (big) {
        float* dst = sums + (size_t)blockIdx.x * NB3;          // private slice
        for (int i = t; i < NB3; i += 256) dst[i] = bins[i];
    } else {
        float* dst = sums + (size_t)(im * 8 + (g & 7)) * NB3;  // shared slice
        for (int i = t; i < NB3; i += 256) unsafeAtomicAdd(&dst[i], bins[i]);
    }
}

// ---------------------------------------------------------------------------
// Finalize: block = image; sum spi slices per ring; mean of (1-frc)^2.
// C_i ring sums are exactly 0 by k -> -k antisymmetry; dropped.
// ---------------------------------------------------------------------------
__global__ __launch_bounds__(256) void finalize(const float* __restrict__ sums,
                                                float* __restrict__ out, int spi) {
    const int b = blockIdx.x, t = threadIdx.x;
    float acc = 0.0f;
    for (int r = t; r < 257; r += 256) {
        float cr = 0.f, c1 = 0.f, c2 = 0.f;
        for (int s = 0; s < spi; ++s) {
            const float* pp = sums + (size_t)(b * spi + s) * NB3 + r * 3;
            cr += pp[0]; c1 += pp[1]; c2 += pp[2];
        }
        float frc = fabsf(cr) / (sqrtf(c1 * c2) + 1e-8f);
        float d = 1.0f - frc;
        acc += d * d;
    }
#pragma unroll
    for (int off = 32; off > 0; off >>= 1) acc += __shfl_down(acc, off);
    __shared__ float red[4];
    if ((t & 63) == 0) red[t >> 6] = acc;
    __syncthreads();
    if (t == 0)
        unsafeAtomicAdd(out, (red[0] + red[1] + red[2] + red[3]) *
                             (1.0f / (257.0f * (float)NIMG)));
}

// ---------------------------------------------------------------------------
extern "C" void kernel_launch(void* const* d_in, const int* in_sizes, int n_in,
                              void* d_out, int out_size, void* d_ws, size_t ws_size,
                              hipStream_t stream) {
    const float* xr = (const float*)d_in[0];   // output: 32x1x512x512 f32
    const float* yr = (const float*)d_in[1];   // target: 32x1x512x512 f32

    float2* Zt = (float2*)d_ws;                                    // 64 MiB
    const size_t ztBytes = ((size_t)NIMG << 18) * sizeof(float2);
    float* sums = (float*)((char*)d_ws + ztBytes);
    const int big = (ws_size >= ztBytes + (size_t)2048 * NB3 * sizeof(float)) ? 1 : 0;

    if (!big)
        hipMemsetAsync(sums, 0, (size_t)NIMG * 8 * NB3 * sizeof(float), stream);
    hipMemsetAsync(d_out, 0, sizeof(float), stream);

    fft_rows_T    <<<dim3(NIMG * 64), dim3(256), 0, stream>>>(xr, yr, Zt);
    fft_cols_rings<<<dim3(NIMG * 64), dim3(256), 0, stream>>>(Zt, sums, big);
    finalize      <<<dim3(NIMG), dim3(256), 0, stream>>>(sums, (float*)d_out, big ? 64 : 8);
}

// Round 2
// 209.473 us; speedup vs baseline: 1.0245x; 1.0234x over previous
//
#include <hip/hip_runtime.h>
#include <math.h>

#define NIMG 32
#define NB3  771             // 257 rings * 3 sums
#define PI_F 3.14159265358979323846f

// ---------------------------------------------------------------------------
__device__ __forceinline__ float2 cadd(float2 a, float2 b){ return make_float2(a.x+b.x, a.y+b.y); }
__device__ __forceinline__ float2 csub(float2 a, float2 b){ return make_float2(a.x-b.x, a.y-b.y); }
__device__ __forceinline__ float2 cmul(float2 a, float2 b){ return make_float2(a.x*b.x - a.y*b.y, a.x*b.y + a.y*b.x); }
__device__ __forceinline__ float2 cmul_mi(float2 a){ return make_float2(a.y, -a.x); }   // * (-i)
__device__ __forceinline__ float2 tw(const float2* T, int m){ return T[m + (m >> 3)]; }
__device__ __forceinline__ int   sw(int pos){ return pos + (pos >> 3); }     // LDS pad swizzle

// 8-point DFT (DIF, natural-order outputs), e^{-2pi i/8} convention
__device__ __forceinline__ void dft8(float2* x) {
    const float c = 0.70710678118654752f;
    float2 u0 = cadd(x[0], x[4]), u1 = cadd(x[1], x[5]);
    float2 u2 = cadd(x[2], x[6]), u3 = cadd(x[3], x[7]);
    float2 v0 = csub(x[0], x[4]);
    float2 d1 = csub(x[1], x[5]);
    float2 v1 = make_float2(c*(d1.x + d1.y), c*(d1.y - d1.x));
    float2 d2 = csub(x[2], x[6]);
    float2 v2 = make_float2(d2.y, -d2.x);
    float2 d3 = csub(x[3], x[7]);
    float2 v3 = make_float2(-c*(d3.x - d3.y), -c*(d3.x + d3.y));
    float2 e0 = cadd(u0,u2), e1 = cadd(u1,u3);
    float2 f0 = csub(u0,u2), f1 = cmul_mi(csub(u1,u3));
    float2 g0 = cadd(v0,v2), g1 = cadd(v1,v3);
    float2 h0 = csub(v0,v2), h1 = cmul_mi(csub(v1,v3));
    x[0] = cadd(e0,e1); x[4] = csub(e0,e1);
    x[2] = cadd(f0,f1); x[6] = csub(f0,f1);
    x[1] = cadd(g0,g1); x[5] = csub(g0,g1);
    x[3] = cadd(h0,h1); x[7] = csub(h0,h1);
}

// ---------------------------------------------------------------------------
// Per-wave 512-pt radix-8 DIF FFT, barrier-free (wave-private 576-slot LDS
// scratch; one wave's LDS ops execute in order). Thread J enters with
// X[q] = x[J + 64q], exits with X[k] = F(64k + r), r = 8*(J&7) + (J>>3).
// ---------------------------------------------------------------------------
__device__ __forceinline__ void wave_fft512(float2* X, float2* Sw,
                                            const float2* T, int J) {
    dft8(X);
#pragma unroll
    for (int k = 1; k < 8; ++k) X[k] = cmul(X[k], tw(T, J * k));
    const int jj = J + (J >> 3);
#pragma unroll
    for (int k = 0; k < 8; ++k) Sw[jj + 72*k] = X[k];

    const int j2 = J & 7;
    const int bb = 72 * (J >> 3) + j2;
#pragma unroll
    for (int q = 0; q < 8; ++q) X[q] = Sw[bb + 9*q];
    dft8(X);
#pragma unroll
    for (int k = 1; k < 8; ++k) X[k] = cmul(X[k], tw(T, 8 * j2 * k));
#pragma unroll
    for (int k = 0; k < 8; ++k) Sw[bb + 9*k] = X[k];

#pragma unroll
    for (int q = 0; q < 8; ++q) X[q] = Sw[9*J + q];
    dft8(X);
}

// ---------------------------------------------------------------------------
// Row pass. Writes transposed Zt[kx][y].
// NOTE r2: __launch_bounds__(256) WITHOUT a min-waves arg. The ",6" variant
// made the allocator clamp to 40 VGPR and spill ~24 B/thread to scratch
// (rocprof r1: WRITE_SIZE 6.2->19.0 MB on the cols kernel carrying the same
// bound), which sat in the dependent FFT chain. Unbounded compiles to ~68
// VGPR (r0 evidence), still <=84 needed for the LDS-limited 6 blocks/CU.
// ---------------------------------------------------------------------------
__global__ __launch_bounds__(256) void fft_rows_T(const float* __restrict__ xr,
                                                  const float* __restrict__ yr,
                                                  float2* __restrict__ Zt) {
    __shared__ float2 S[4 * 576];
    __shared__ float2 T[576];
    const int t = threadIdx.x, w = t >> 6, J = t & 63;
    const int im = blockIdx.x >> 6, grp = blockIdx.x & 63;

#pragma unroll
    for (int i = 0; i < 2; ++i) {
        const int m = t + 256 * i;
        float s, c;
        __sincosf(-2.0f * PI_F * (float)m / 512.0f, &s, &c);
        T[m + (m >> 3)] = make_float2(c, s);
    }

    const size_t b0 = ((size_t)(im * 512 + grp * 8 + w)) << 9;
    const size_t b1 = b0 + (4u << 9);
    float2 X0[8], X1[8];
#pragma unroll
    for (int q = 0; q < 8; ++q) {
        X0[q] = make_float2(xr[b0 + J + 64*q], yr[b0 + J + 64*q]);
        X1[q] = make_float2(xr[b1 + J + 64*q], yr[b1 + J + 64*q]);
    }
    __syncthreads();                       // T ready

    float2* Sw = S + w * 576;
    wave_fft512(X0, Sw, T, J);
    wave_fft512(X1, Sw, T, J);

    const int r = ((J & 7) << 3) | (J >> 3);

#pragma unroll
    for (int k = 0; k < 8; ++k) Sw[64*k + r] = X0[k];
    __syncthreads();
    float2 eA[4], eB[4];
#pragma unroll
    for (int j = 0; j < 4; ++j) { eA[j] = S[j*576 + t]; eB[j] = S[j*576 + t + 256]; }
    __syncthreads();

#pragma unroll
    for (int k = 0; k < 8; ++k) Sw[64*k + r] = X1[k];
    __syncthreads();

    const size_t zb = ((size_t)im << 18) + (grp << 3);
    {
        float4* o = (float4*)(Zt + zb + ((size_t)t << 9));
        float2 f0 = S[0*576 + t], f1 = S[1*576 + t];
        float2 f2 = S[2*576 + t], f3 = S[3*576 + t];
        o[0] = make_float4(eA[0].x, eA[0].y, eA[1].x, eA[1].y);
        o[1] = make_float4(eA[2].x, eA[2].y, eA[3].x, eA[3].y);
        o[2] = make_float4(f0.x, f0.y, f1.x, f1.y);
        o[3] = make_float4(f2.x, f2.y, f3.x, f3.y);
    }
    {
        float4* o = (float4*)(Zt + zb + ((size_t)(t + 256) << 9));
        float2 f0 = S[0*576 + t + 256], f1 = S[1*576 + t + 256];
        float2 f2 = S[2*576 + t + 256], f3 = S[3*576 + t + 256];
        o[0] = make_float4(eB[0].x, eB[0].y, eB[1].x, eB[1].y);
        o[1] = make_float4(eB[2].x, eB[2].y, eB[3].x, eB[3].y);
        o[2] = make_float4(f0.x, f0.y, f1.x, f1.y);
        o[3] = make_float4(f2.x, f2.y, f3.x, f3.y);
    }
}

// ---------------------------------------------------------------------------
// Fused column FFT + rings, v4 = v3 layout (ONE 576-slot scratch per wave,
// 26.6 KB LDS -> 6 blocks/CU, occupancy 29.7% measured r1) with the spill
// regression fixed: no min-waves clamp in __launch_bounds__.
// ---------------------------------------------------------------------------
__global__ __launch_bounds__(256) void fft_cols_rings(const float2* __restrict__ Zt,
                                                      float* __restrict__ sums,
                                                      int big) {
    __shared__ float2 S[4 * 576];      // 1 region per wave: 18,432 B
    __shared__ float2 T[576];          //  4,608 B
    __shared__ float  bins[258 * 3];   //  3,096 B
    const int t = threadIdx.x, w = t >> 6, J = t & 63;
    const int im = blockIdx.x >> 6, g = blockIdx.x & 63;
    const int p = 4 * g + w;

#pragma unroll
    for (int i = 0; i < 2; ++i) {
        const int m = t + 256 * i;
        float s, c;
        __sincosf(-2.0f * PI_F * (float)m / 512.0f, &s, &c);
        T[m + (m >> 3)] = make_float2(c, s);
    }
    for (int i = t; i < 258 * 3; i += 256) bins[i] = 0.0f;

    const int c0 = (p == 0) ? 0   : p;
    const int c1 = (p == 0) ? 256 : 512 - p;
    const float2* rp0 = Zt + ((size_t)im << 18) + ((size_t)c0 << 9);
    const float2* rp1 = Zt + ((size_t)im << 18) + ((size_t)c1 << 9);
    float2 X0[8], X1[8];
#pragma unroll
    for (int q = 0; q < 8; ++q) { X0[q] = rp0[J + 64*q]; X1[q] = rp1[J + 64*q]; }
    __syncthreads();                       // T ready, bins zeroed

    float2* A = S + w * 576;               // single wave-private region
    const int r  = ((J & 7) << 3) | (J >> 3);
    const int pk = r + (r >> 3);           // sw(64k + r) = 72k + pk

    const float scale = 1.0f / (512.0f * 512.0f);
    auto pix = [&](float2 zk, float2 zm, float& av, float& c1v, float& c2v) {
        float f1r = 0.5f * (zk.x + zm.x) * scale;
        float f1i = 0.5f * (zk.y - zm.y) * scale;
        float f2r = 0.5f * (zk.y + zm.y) * scale;
        float f2i = 0.5f * (zm.x - zk.x) * scale;
        av  = f1r * f2r + f1i * f2i;
        c1v = f1r * f1r + f1i * f1i;
        c2v = f2r * f2r + f2i * f2i;
    };
    auto flush = [&](int ring, float a, float b, float c) {
        if (ring >= 0 && ring <= 256) {
            unsafeAtomicAdd(&bins[ring*3+0], a);
            unsafeAtomicAdd(&bins[ring*3+1], b);
            unsafeAtomicAdd(&bins[ring*3+2], c);
        }
    };

    // ---- column A: FFT + park (natural order, swizzled)
    wave_fft512(X0, A, T, J);
#pragma unroll
    for (int k = 0; k < 8; ++k) A[72*k + pk] = X0[k];

    float2 asv[8];                         // p>=1: mirror values saved across B's FFT
    if (p == 0) {
        // col 0 is self-mirror: process its rings now, straight from A.
        int cur0 = -1;
        float a0 = 0, b0 = 0, c0v = 0;
#pragma unroll
        for (int i = 0; i < 8; ++i) {
            const int ky  = 8*J + i;
            const int kyp = (512 - ky) & 511;
            float2 zk = A[sw(ky)], zm = A[sw(kyp)];
            const float fk = (ky < 256) ? (float)ky : (float)(ky - 512);
            float av, cv, dv;
            pix(zk, zm, av, cv, dv);                       // col 0, fy = 0
            int rr = (int)rintf(fabsf(fk)); if (rr > 256) rr = 257;
            if (rr != cur0) { flush(cur0, a0, b0, c0v); cur0 = rr; a0 = av; b0 = cv; c0v = dv; }
            else            { a0 += av; b0 += cv; c0v += dv; }
        }
        flush(cur0, a0, b0, c0v);
    } else {
        // Save A[sw(8J+i)] = A[9J+i], i=0..7 (contiguous) before reuse.
#pragma unroll
        for (int i = 0; i < 8; ++i) asv[i] = A[9*J + i];
    }

    // ---- column B: FFT + park in the SAME region (in-wave order is safe:
    //      the asv/ring reads above were issued before these writes)
    wave_fft512(X1, A, T, J);
#pragma unroll
    for (int k = 0; k < 8; ++k) A[72*k + pk] = X1[k];

    if (p == 0) {
        // col 256 is self-mirror too (512-256 = 256): rings from A (= col 256).
        int cur1 = -1;
        float a1 = 0, b1 = 0, c1v = 0;
#pragma unroll
        for (int i = 0; i < 8; ++i) {
            const int ky  = 8*J + i;
            const int kyp = (512 - ky) & 511;
            float2 zk = A[sw(ky)], zm = A[sw(kyp)];
            const float fk = (ky < 256) ? (float)ky : (float)(ky - 512);
            float av, cv, dv;
            pix(zk, zm, av, cv, dv);                       // col 256, fy = 256
            int rr = (int)rintf(sqrtf(fk*fk + 65536.0f)); if (rr > 256) rr = 257;
            if (rr != cur1) { flush(cur1, a1, b1, c1v); cur1 = rr; a1 = av; b1 = cv; c1v = dv; }
            else            { a1 += av; b1 += cv; c1v += dv; }
        }
        flush(cur1, a1, b1, c1v);
    } else {
        const float fy2 = (float)p * (float)p;
        int curR = -1;
        float sA = 0, sB = 0, sC = 0;
#pragma unroll
        for (int i = 0; i < 8; ++i) {
            const int ky  = 8*J + i;
            const int kyp = (512 - ky) & 511;
            float2 zk = asv[i];              // P0[ky]            (saved from col A)
            float2 zm = A[sw(kyp)];          // P1[512-ky]        (col B, parked)
            float a1v, b1v, d1v, a2v, b2v, d2v;
            pix(zk, zm, a1v, b1v, d1v);      // pixel (p, ky),        partner (512-p, 512-ky)
            pix(zm, zk, a2v, b2v, d2v);      // pixel (512-p,512-ky), partner (p, ky)
            const float fk = (ky < 256) ? (float)ky : (float)(ky - 512);
            int rr = (int)rintf(sqrtf(fk*fk + fy2)); if (rr > 256) rr = 257;
            const float aa = a1v + a2v, bb = b1v + b2v, cc = d1v + d2v;
            if (rr != curR) { flush(curR, sA, sB, sC); curR = rr; sA = aa; sB = bb; sC = cc; }
            else            { sA += aa; sB += bb; sC += cc; }
        }
        flush(curR, sA, sB, sC);
    }
    __syncthreads();

    if (big) {
        float* dst = sums + (size_t)blockIdx.x * NB3;          // private slice
        for (int i = t; i < NB3; i += 256) dst[i] = bins[i];
    } else {
        float* dst = sums + (size_t)(im * 8 + (g & 7)) * NB3;  // shared slice
        for (int i = t; i < NB3; i += 256) unsafeAtomicAdd(&dst[i], bins[i]);
    }
}

// ---------------------------------------------------------------------------
// Finalize: block = image; sum spi slices per ring; mean of (1-frc)^2.
// C_i ring sums are exactly 0 by k -> -k antisymmetry; dropped.
// ---------------------------------------------------------------------------
__global__ __launch_bounds__(256) void finalize(const float* __restrict__ sums,
                                                float* __restrict__ out, int spi) {
    const int b = blockIdx.x, t = threadIdx.x;
    float acc = 0.0f;
    for (int r = t; r < 257; r += 256) {
        float cr = 0.f, c1 = 0.f, c2 = 0.f;
        for (int s = 0; s < spi; ++s) {
            const float* pp = sums + (size_t)(b * spi + s) * NB3 + r * 3;
            cr += pp[0]; c1 += pp[1]; c2 += pp[2];
        }
        float frc = fabsf(cr) / (sqrtf(c1 * c2) + 1e-8f);
        float d = 1.0f - frc;
        acc += d * d;
    }
#pragma unroll
    for (int off = 32; off > 0; off >>= 1) acc += __shfl_down(acc, off);
    __shared__ float red[4];
    if ((t & 63) == 0) red[t >> 6] = acc;
    __syncthreads();
    if (t == 0)
        unsafeAtomicAdd(out, (red[0] + red[1] + red[2] + red[3]) *
                             (1.0f / (257.0f * (float)NIMG)));
}

// ---------------------------------------------------------------------------
extern "C" void kernel_launch(void* const* d_in, const int* in_sizes, int n_in,
                              void* d_out, int out_size, void* d_ws, size_t ws_size,
                              hipStream_t stream) {
    const float* xr = (const float*)d_in[0];   // output: 32x1x512x512 f32
    const float* yr = (const float*)d_in[1];   // target: 32x1x512x512 f32

    float2* Zt = (float2*)d_ws;                                    // 64 MiB
    const size_t ztBytes = ((size_t)NIMG << 18) * sizeof(float2);
    float* sums = (float*)((char*)d_ws + ztBytes);
    const int big = (ws_size >= ztBytes + (size_t)2048 * NB3 * sizeof(float)) ? 1 : 0;

    if (!big)
        hipMemsetAsync(sums, 0, (size_t)NIMG * 8 * NB3 * sizeof(float), stream);
    hipMemsetAsync(d_out, 0, sizeof(float), stream);

    fft_rows_T    <<<dim3(NIMG * 64), dim3(256), 0, stream>>>(xr, yr, Zt);
    fft_cols_rings<<<dim3(NIMG * 64), dim3(256), 0, stream>>>(Zt, sums, big);
    finalize      <<<dim3(NIMG), dim3(256), 0, stream>>>(sums, (float*)d_out, big ? 64 : 8);
}

// Round 3
// 207.335 us; speedup vs baseline: 1.0351x; 1.0103x over previous
//
#include <hip/hip_runtime.h>
#include <math.h>

#define NIMG 32
#define NB3  771             // 257 rings * 3 sums
#define PI_F 3.14159265358979323846f

// ---------------------------------------------------------------------------
__device__ __forceinline__ float2 cadd(float2 a, float2 b){ return make_float2(a.x+b.x, a.y+b.y); }
__device__ __forceinline__ float2 csub(float2 a, float2 b){ return make_float2(a.x-b.x, a.y-b.y); }
__device__ __forceinline__ float2 cmul(float2 a, float2 b){ return make_float2(a.x*b.x - a.y*b.y, a.x*b.y + a.y*b.x); }
__device__ __forceinline__ float2 cmul_mi(float2 a){ return make_float2(a.y, -a.x); }   // * (-i)
__device__ __forceinline__ float2 tw(const float2* T, int m){ return T[m + (m >> 3)]; }
__device__ __forceinline__ int   sw(int pos){ return pos + (pos >> 3); }     // LDS pad swizzle

// 8-point DFT (DIF, natural-order outputs), e^{-2pi i/8} convention
__device__ __forceinline__ void dft8(float2* x) {
    const float c = 0.70710678118654752f;
    float2 u0 = cadd(x[0], x[4]), u1 = cadd(x[1], x[5]);
    float2 u2 = cadd(x[2], x[6]), u3 = cadd(x[3], x[7]);
    float2 v0 = csub(x[0], x[4]);
    float2 d1 = csub(x[1], x[5]);
    float2 v1 = make_float2(c*(d1.x + d1.y), c*(d1.y - d1.x));
    float2 d2 = csub(x[2], x[6]);
    float2 v2 = make_float2(d2.y, -d2.x);
    float2 d3 = csub(x[3], x[7]);
    float2 v3 = make_float2(-c*(d3.x - d3.y), -c*(d3.x + d3.y));
    float2 e0 = cadd(u0,u2), e1 = cadd(u1,u3);
    float2 f0 = csub(u0,u2), f1 = cmul_mi(csub(u1,u3));
    float2 g0 = cadd(v0,v2), g1 = cadd(v1,v3);
    float2 h0 = csub(v0,v2), h1 = cmul_mi(csub(v1,v3));
    x[0] = cadd(e0,e1); x[4] = csub(e0,e1);
    x[2] = cadd(f0,f1); x[6] = csub(f0,f1);
    x[1] = cadd(g0,g1); x[5] = csub(g0,g1);
    x[3] = cadd(h0,h1); x[7] = csub(h0,h1);
}

// ---------------------------------------------------------------------------
// DUAL per-wave 512-pt radix-8 DIF FFT (r3): two independent chains (Xa, Xb)
// interleaved at stage granularity, SHARING one 576-slot wave-private scratch.
// Safety: the wave-wide in-order LDS pipe guarantees readA (issued before
// writeB) observes pre-B data even though writeB hits the same slots — the
// same guarantee v3's asv-reuse already relied on. The compiler emits counted
// lgkmcnt waits, so chain A's dft8 runs while chain B's 16 LDS ops are in
// flight: each LDS-latency wait hides the other chain's compute.
// Rationale (rocprof r0 vs r2): doubling resident waves (occ 17.8->27.7%)
// gained only 4% -> occupancy is NOT the limiter; the per-wave serial chain
// is. This doubles intra-wave ILP at zero LDS cost.
// Thread J enters with X[q] = x[J + 64q], exits with X[k] = F(64k + r),
// r = 8*(J&7) + (J>>3).
// ---------------------------------------------------------------------------
__device__ __forceinline__ void wave_fft512_dual(float2* Xa, float2* Xb,
                                                 float2* Sw, const float2* T,
                                                 int J) {
    dft8(Xa);
    dft8(Xb);
#pragma unroll
    for (int k = 1; k < 8; ++k) Xa[k] = cmul(Xa[k], tw(T, J * k));
#pragma unroll
    for (int k = 1; k < 8; ++k) Xb[k] = cmul(Xb[k], tw(T, J * k));
    const int jj = J + (J >> 3);
    const int j2 = J & 7;
    const int bb = 72 * (J >> 3) + j2;

    // stage 1 -> 2 transpose, A then B through the SAME region (in-order pipe)
#pragma unroll
    for (int k = 0; k < 8; ++k) Sw[jj + 72*k] = Xa[k];
#pragma unroll
    for (int q = 0; q < 8; ++q) Xa[q] = Sw[bb + 9*q];
#pragma unroll
    for (int k = 0; k < 8; ++k) Sw[jj + 72*k] = Xb[k];
#pragma unroll
    for (int q = 0; q < 8; ++q) Xb[q] = Sw[bb + 9*q];

    dft8(Xa);
    dft8(Xb);
#pragma unroll
    for (int k = 1; k < 8; ++k) Xa[k] = cmul(Xa[k], tw(T, 8 * j2 * k));
#pragma unroll
    for (int k = 1; k < 8; ++k) Xb[k] = cmul(Xb[k], tw(T, 8 * j2 * k));

    // stage 2 -> 3 transpose
#pragma unroll
    for (int k = 0; k < 8; ++k) Sw[bb + 9*k] = Xa[k];
#pragma unroll
    for (int q = 0; q < 8; ++q) Xa[q] = Sw[9*J + q];
#pragma unroll
    for (int k = 0; k < 8; ++k) Sw[bb + 9*k] = Xb[k];
#pragma unroll
    for (int q = 0; q < 8; ++q) Xb[q] = Sw[9*J + q];

    dft8(Xa);
    dft8(Xb);
}

// ---------------------------------------------------------------------------
// Row pass. Writes transposed Zt[kx][y].
// __launch_bounds__(256) with NO min-waves arg: the ",6" variant clamped the
// allocator to 40 VGPR and spilled ~24 B/thread to scratch (rocprof r1:
// WRITE_SIZE 6.2->19.0 MB). Let VGPR float.
// ---------------------------------------------------------------------------
__global__ __launch_bounds__(256) void fft_rows_T(const float* __restrict__ xr,
                                                  const float* __restrict__ yr,
                                                  float2* __restrict__ Zt) {
    __shared__ float2 S[4 * 576];
    __shared__ float2 T[576];
    const int t = threadIdx.x, w = t >> 6, J = t & 63;
    const int im = blockIdx.x >> 6, grp = blockIdx.x & 63;

#pragma unroll
    for (int i = 0; i < 2; ++i) {
        const int m = t + 256 * i;
        float s, c;
        __sincosf(-2.0f * PI_F * (float)m / 512.0f, &s, &c);
        T[m + (m >> 3)] = make_float2(c, s);
    }

    const size_t b0 = ((size_t)(im * 512 + grp * 8 + w)) << 9;
    const size_t b1 = b0 + (4u << 9);
    float2 X0[8], X1[8];
#pragma unroll
    for (int q = 0; q < 8; ++q) {
        X0[q] = make_float2(xr[b0 + J + 64*q], yr[b0 + J + 64*q]);
        X1[q] = make_float2(xr[b1 + J + 64*q], yr[b1 + J + 64*q]);
    }
    __syncthreads();                       // T ready

    float2* Sw = S + w * 576;
    wave_fft512_dual(X0, X1, Sw, T, J);

    const int r = ((J & 7) << 3) | (J >> 3);

#pragma unroll
    for (int k = 0; k < 8; ++k) Sw[64*k + r] = X0[k];
    __syncthreads();
    float2 eA[4], eB[4];
#pragma unroll
    for (int j = 0; j < 4; ++j) { eA[j] = S[j*576 + t]; eB[j] = S[j*576 + t + 256]; }
    __syncthreads();

#pragma unroll
    for (int k = 0; k < 8; ++k) Sw[64*k + r] = X1[k];
    __syncthreads();

    const size_t zb = ((size_t)im << 18) + (grp << 3);
    {
        float4* o = (float4*)(Zt + zb + ((size_t)t << 9));
        float2 f0 = S[0*576 + t], f1 = S[1*576 + t];
        float2 f2 = S[2*576 + t], f3 = S[3*576 + t];
        o[0] = make_float4(eA[0].x, eA[0].y, eA[1].x, eA[1].y);
        o[1] = make_float4(eA[2].x, eA[2].y, eA[3].x, eA[3].y);
        o[2] = make_float4(f0.x, f0.y, f1.x, f1.y);
        o[3] = make_float4(f2.x, f2.y, f3.x, f3.y);
    }
    {
        float4* o = (float4*)(Zt + zb + ((size_t)(t + 256) << 9));
        float2 f0 = S[0*576 + t + 256], f1 = S[1*576 + t + 256];
        float2 f2 = S[2*576 + t + 256], f3 = S[3*576 + t + 256];
        o[0] = make_float4(eB[0].x, eB[0].y, eB[1].x, eB[1].y);
        o[1] = make_float4(eB[2].x, eB[2].y, eB[3].x, eB[3].y);
        o[2] = make_float4(f0.x, f0.y, f1.x, f1.y);
        o[3] = make_float4(f2.x, f2.y, f3.x, f3.y);
    }
}

// ---------------------------------------------------------------------------
// Fused column FFT + rings, v5 = v4 layout (ONE 576-slot scratch per wave,
// 26.6 KB LDS) + dual-interleaved FFT. Ring phase identical to v3/v4:
// park A, save 8 mirror values to regs, park B over the same region (in-wave
// LDS order makes the overwrite safe), then run-merged LDS-atomic deposits.
// ---------------------------------------------------------------------------
__global__ __launch_bounds__(256) void fft_cols_rings(const float2* __restrict__ Zt,
                                                      float* __restrict__ sums,
                                                      int big) {
    __shared__ float2 S[4 * 576];      // 1 region per wave: 18,432 B
    __shared__ float2 T[576];          //  4,608 B
    __shared__ float  bins[258 * 3];   //  3,096 B
    const int t = threadIdx.x, w = t >> 6, J = t & 63;
    const int im = blockIdx.x >> 6, g = blockIdx.x & 63;
    const int p = 4 * g + w;

#pragma unroll
    for (int i = 0; i < 2; ++i) {
        const int m = t + 256 * i;
        float s, c;
        __sincosf(-2.0f * PI_F * (float)m / 512.0f, &s, &c);
        T[m + (m >> 3)] = make_float2(c, s);
    }
    for (int i = t; i < 258 * 3; i += 256) bins[i] = 0.0f;

    const int c0 = (p == 0) ? 0   : p;
    const int c1 = (p == 0) ? 256 : 512 - p;
    const float2* rp0 = Zt + ((size_t)im << 18) + ((size_t)c0 << 9);
    const float2* rp1 = Zt + ((size_t)im << 18) + ((size_t)c1 << 9);
    float2 X0[8], X1[8];
#pragma unroll
    for (int q = 0; q < 8; ++q) { X0[q] = rp0[J + 64*q]; X1[q] = rp1[J + 64*q]; }
    __syncthreads();                       // T ready, bins zeroed

    float2* A = S + w * 576;               // single wave-private region
    const int r  = ((J & 7) << 3) | (J >> 3);
    const int pk = r + (r >> 3);           // sw(64k + r) = 72k + pk

    const float scale = 1.0f / (512.0f * 512.0f);
    auto pix = [&](float2 zk, float2 zm, float& av, float& c1v, float& c2v) {
        float f1r = 0.5f * (zk.x + zm.x) * scale;
        float f1i = 0.5f * (zk.y - zm.y) * scale;
        float f2r = 0.5f * (zk.y + zm.y) * scale;
        float f2i = 0.5f * (zm.x - zk.x) * scale;
        av  = f1r * f2r + f1i * f2i;
        c1v = f1r * f1r + f1i * f1i;
        c2v = f2r * f2r + f2i * f2i;
    };
    auto flush = [&](int ring, float a, float b, float c) {
        if (ring >= 0 && ring <= 256) {
            unsafeAtomicAdd(&bins[ring*3+0], a);
            unsafeAtomicAdd(&bins[ring*3+1], b);
            unsafeAtomicAdd(&bins[ring*3+2], c);
        }
    };

    // ---- both column FFTs, interleaved, one scratch region
    wave_fft512_dual(X0, X1, A, T, J);

    // ---- park A (natural order, swizzled)
#pragma unroll
    for (int k = 0; k < 8; ++k) A[72*k + pk] = X0[k];

    float2 asv[8];                         // p>=1: mirror values saved across B's park
    if (p == 0) {
        // col 0 is self-mirror: process its rings now, straight from A
        // (reads issue before park-B's writes -> in-order safe).
        int cur0 = -1;
        float a0 = 0, b0 = 0, c0v = 0;
#pragma unroll
        for (int i = 0; i < 8; ++i) {
            const int ky  = 8*J + i;
            const int kyp = (512 - ky) & 511;
            float2 zk = A[sw(ky)], zm = A[sw(kyp)];
            const float fk = (ky < 256) ? (float)ky : (float)(ky - 512);
            float av, cv, dv;
            pix(zk, zm, av, cv, dv);                       // col 0, fy = 0
            int rr = (int)rintf(fabsf(fk)); if (rr > 256) rr = 257;
            if (rr != cur0) { flush(cur0, a0, b0, c0v); cur0 = rr; a0 = av; b0 = cv; c0v = dv; }
            else            { a0 += av; b0 += cv; c0v += dv; }
        }
        flush(cur0, a0, b0, c0v);
    } else {
        // Save A[sw(8J+i)] = A[9J+i], i=0..7 (contiguous) before reuse.
#pragma unroll
        for (int i = 0; i < 8; ++i) asv[i] = A[9*J + i];
    }

    // ---- park B in the SAME region (in-wave order: reads above precede these)
#pragma unroll
    for (int k = 0; k < 8; ++k) A[72*k + pk] = X1[k];

    if (p == 0) {
        // col 256 is self-mirror too (512-256 = 256): rings from A (= col 256).
        int cur1 = -1;
        float a1 = 0, b1 = 0, c1v = 0;
#pragma unroll
        for (int i = 0; i < 8; ++i) {
            const int ky  = 8*J + i;
            const int kyp = (512 - ky) & 511;
            float2 zk = A[sw(ky)], zm = A[sw(kyp)];
            const float fk = (ky < 256) ? (float)ky : (float)(ky - 512);
            float av, cv, dv;
            pix(zk, zm, av, cv, dv);                       // col 256, fy = 256
            int rr = (int)rintf(sqrtf(fk*fk + 65536.0f)); if (rr > 256) rr = 257;
            if (rr != cur1) { flush(cur1, a1, b1, c1v); cur1 = rr; a1 = av; b1 = cv; c1v = dv; }
            else            { a1 += av; b1 += cv; c1v += dv; }
        }
        flush(cur1, a1, b1, c1v);
    } else {
        const float fy2 = (float)p * (float)p;
        int curR = -1;
        float sA = 0, sB = 0, sC = 0;
#pragma unroll
        for (int i = 0; i < 8; ++i) {
            const int ky  = 8*J + i;
            const int kyp = (512 - ky) & 511;
            float2 zk = asv[i];              // P0[ky]            (saved from col A)
            float2 zm = A[sw(kyp)];          // P1[512-ky]        (col B, parked)
            float a1v, b1v, d1v, a2v, b2v, d2v;
            pix(zk, zm, a1v, b1v, d1v);      // pixel (p, ky),        partner (512-p, 512-ky)
            pix(zm, zk, a2v, b2v, d2v);      // pixel (512-p,512-ky), partner (p, ky)
            const float fk = (ky < 256) ? (float)ky : (float)(ky - 512);
            int rr = (int)rintf(sqrtf(fk*fk + fy2)); if (rr > 256) rr = 257;
            const float aa = a1v + a2v, bb = b1v + b2v, cc = d1v + d2v;
            if (rr != curR) { flush(curR, sA, sB, sC); curR = rr; sA = aa; sB = bb; sC = cc; }
            else            { sA += aa; sB += bb; sC += cc; }
        }
        flush(curR, sA, sB, sC);
    }
    __syncthreads();

    if (big) {
        float* dst = sums + (size_t)blockIdx.x * NB3;          // private slice
        for (int i = t; i < NB3; i += 256) dst[i] = bins[i];
    } else {
        float* dst = sums + (size_t)(im * 8 + (g & 7)) * NB3;  // shared slice
        for (int i = t; i < NB3; i += 256) unsafeAtomicAdd(&dst[i], bins[i]);
    }
}

// ---------------------------------------------------------------------------
// Finalize: block = image; sum spi slices per ring; mean of (1-frc)^2.
// C_i ring sums are exactly 0 by k -> -k antisymmetry; dropped.
// ---------------------------------------------------------------------------
__global__ __launch_bounds__(256) void finalize(const float* __restrict__ sums,
                                                float* __restrict__ out, int spi) {
    const int b = blockIdx.x, t = threadIdx.x;
    float acc = 0.0f;
    for (int r = t; r < 257; r += 256) {
        float cr = 0.f, c1 = 0.f, c2 = 0.f;
        for (int s = 0; s < spi; ++s) {
            const float* pp = sums + (size_t)(b * spi + s) * NB3 + r * 3;
            cr += pp[0]; c1 += pp[1]; c2 += pp[2];
        }
        float frc = fabsf(cr) / (sqrtf(c1 * c2) + 1e-8f);
        float d = 1.0f - frc;
        acc += d * d;
    }
#pragma unroll
    for (int off = 32; off > 0; off >>= 1) acc += __shfl_down(acc, off);
    __shared__ float red[4];
    if ((t & 63) == 0) red[t >> 6] = acc;
    __syncthreads();
    if (t == 0)
        unsafeAtomicAdd(out, (red[0] + red[1] + red[2] + red[3]) *
                             (1.0f / (257.0f * (float)NIMG)));
}

// ---------------------------------------------------------------------------
extern "C" void kernel_launch(void* const* d_in, const int* in_sizes, int n_in,
                              void* d_out, int out_size, void* d_ws, size_t ws_size,
                              hipStream_t stream) {
    const float* xr = (const float*)d_in[0];   // output: 32x1x512x512 f32
    const float* yr = (const float*)d_in[1];   // target: 32x1x512x512 f32

    float2* Zt = (float2*)d_ws;                                    // 64 MiB
    const size_t ztBytes = ((size_t)NIMG << 18) * sizeof(float2);
    float* sums = (float*)((char*)d_ws + ztBytes);
    const int big = (ws_size >= ztBytes + (size_t)2048 * NB3 * sizeof(float)) ? 1 : 0;

    if (!big)
        hipMemsetAsync(sums, 0, (size_t)NIMG * 8 * NB3 * sizeof(float), stream);
    hipMemsetAsync(d_out, 0, sizeof(float), stream);

    fft_rows_T    <<<dim3(NIMG * 64), dim3(256), 0, stream>>>(xr, yr, Zt);
    fft_cols_rings<<<dim3(NIMG * 64), dim3(256), 0, stream>>>(Zt, sums, big);
    finalize      <<<dim3(NIMG), dim3(256), 0, stream>>>(sums, (float*)d_out, big ? 64 : 8);
}

// Round 4
// 202.073 us; speedup vs baseline: 1.0620x; 1.0260x over previous
//
#include <hip/hip_runtime.h>
#include <math.h>

#define NIMG 32
#define NB3  771             // 257 rings * 3 sums
#define NSLICE (NIMG * 8)    // 8 shared slices per image, global-atomic accumulated
#define PI_F 3.14159265358979323846f

// ---------------------------------------------------------------------------
__device__ __forceinline__ float2 cadd(float2 a, float2 b){ return make_float2(a.x+b.x, a.y+b.y); }
__device__ __forceinline__ float2 csub(float2 a, float2 b){ return make_float2(a.x-b.x, a.y-b.y); }
__device__ __forceinline__ float2 cmul(float2 a, float2 b){ return make_float2(a.x*b.x - a.y*b.y, a.x*b.y + a.y*b.x); }
__device__ __forceinline__ float2 cmul_mi(float2 a){ return make_float2(a.y, -a.x); }   // * (-i)
__device__ __forceinline__ float2 tw(const float2* T, int m){ return T[m + (m >> 3)]; }
__device__ __forceinline__ int   sw(int pos){ return pos + (pos >> 3); }     // LDS pad swizzle

// 8-point DFT (DIF, natural-order outputs), e^{-2pi i/8} convention
__device__ __forceinline__ void dft8(float2* x) {
    const float c = 0.70710678118654752f;
    float2 u0 = cadd(x[0], x[4]), u1 = cadd(x[1], x[5]);
    float2 u2 = cadd(x[2], x[6]), u3 = cadd(x[3], x[7]);
    float2 v0 = csub(x[0], x[4]);
    float2 d1 = csub(x[1], x[5]);
    float2 v1 = make_float2(c*(d1.x + d1.y), c*(d1.y - d1.x));
    float2 d2 = csub(x[2], x[6]);
    float2 v2 = make_float2(d2.y, -d2.x);
    float2 d3 = csub(x[3], x[7]);
    float2 v3 = make_float2(-c*(d3.x - d3.y), -c*(d3.x + d3.y));
    float2 e0 = cadd(u0,u2), e1 = cadd(u1,u3);
    float2 f0 = csub(u0,u2), f1 = cmul_mi(csub(u1,u3));
    float2 g0 = cadd(v0,v2), g1 = cadd(v1,v3);
    float2 h0 = csub(v0,v2), h1 = cmul_mi(csub(v1,v3));
    x[0] = cadd(e0,e1); x[4] = csub(e0,e1);
    x[2] = cadd(f0,f1); x[6] = csub(f0,f1);
    x[1] = cadd(g0,g1); x[5] = csub(g0,g1);
    x[3] = cadd(h0,h1); x[7] = csub(h0,h1);
}

// ---------------------------------------------------------------------------
// DUAL per-wave 512-pt radix-8 DIF FFT: two independent chains interleaved,
// sharing one 576-slot wave-private scratch (in-order LDS pipe makes the
// readA-before-writeB overlap safe). Thread J enters with X[q] = x[J+64q],
// exits with X[k] = F(64k + r), r = 8*(J&7) + (J>>3).
// ---------------------------------------------------------------------------
__device__ __forceinline__ void wave_fft512_dual(float2* Xa, float2* Xb,
                                                 float2* Sw, const float2* T,
                                                 int J) {
    dft8(Xa);
    dft8(Xb);
#pragma unroll
    for (int k = 1; k < 8; ++k) Xa[k] = cmul(Xa[k], tw(T, J * k));
#pragma unroll
    for (int k = 1; k < 8; ++k) Xb[k] = cmul(Xb[k], tw(T, J * k));
    const int jj = J + (J >> 3);
    const int j2 = J & 7;
    const int bb = 72 * (J >> 3) + j2;

#pragma unroll
    for (int k = 0; k < 8; ++k) Sw[jj + 72*k] = Xa[k];
#pragma unroll
    for (int q = 0; q < 8; ++q) Xa[q] = Sw[bb + 9*q];
#pragma unroll
    for (int k = 0; k < 8; ++k) Sw[jj + 72*k] = Xb[k];
#pragma unroll
    for (int q = 0; q < 8; ++q) Xb[q] = Sw[bb + 9*q];

    dft8(Xa);
    dft8(Xb);
#pragma unroll
    for (int k = 1; k < 8; ++k) Xa[k] = cmul(Xa[k], tw(T, 8 * j2 * k));
#pragma unroll
    for (int k = 1; k < 8; ++k) Xb[k] = cmul(Xb[k], tw(T, 8 * j2 * k));

#pragma unroll
    for (int k = 0; k < 8; ++k) Sw[bb + 9*k] = Xa[k];
#pragma unroll
    for (int q = 0; q < 8; ++q) Xa[q] = Sw[9*J + q];
#pragma unroll
    for (int k = 0; k < 8; ++k) Sw[bb + 9*k] = Xb[k];
#pragma unroll
    for (int q = 0; q < 8; ++q) Xb[q] = Sw[9*J + q];

    dft8(Xa);
    dft8(Xb);
}

// ---------------------------------------------------------------------------
// Row pass. r4: Zt layout changed to [im][ygrp=y>>3][kx][yin=y&7] (float2
// units: im<<18 | ygrp<<12 | kx<<3 | yin). Old layout made each thread store
// 64 B at 4 KB stride (half-line partials, no write-combining across blocks).
// New layout: a wave's stores are 64 lanes x 64 B CONTIGUOUS = 4 KB full
// lines per store instruction. Cols absorbs the (8x64B)-segment gather.
// Also: blocks 0..255 zero one sums slice each; block 0 resets the tail
// counter (visible to cols via end-of-kernel L2 flush — same guarantee the
// Zt handoff already relies on).
// ---------------------------------------------------------------------------
__global__ __launch_bounds__(256) void fft_rows_T(const float* __restrict__ xr,
                                                  const float* __restrict__ yr,
                                                  float2* __restrict__ Zt,
                                                  float* __restrict__ sums,
                                                  unsigned int* __restrict__ counter) {
    __shared__ float2 S[4 * 576];
    __shared__ float2 T[576];
    const int t = threadIdx.x, w = t >> 6, J = t & 63;
    const int im = blockIdx.x >> 6, grp = blockIdx.x & 63;

    if (blockIdx.x < NSLICE) {
        float* z = sums + (size_t)blockIdx.x * NB3;
        for (int i = t; i < NB3; i += 256) z[i] = 0.0f;
        if (blockIdx.x == 0 && t == 0) *counter = 0u;
    }

#pragma unroll
    for (int i = 0; i < 2; ++i) {
        const int m = t + 256 * i;
        float s, c;
        __sincosf(-2.0f * PI_F * (float)m / 512.0f, &s, &c);
        T[m + (m >> 3)] = make_float2(c, s);
    }

    const size_t b0 = ((size_t)(im * 512 + grp * 8 + w)) << 9;
    const size_t b1 = b0 + (4u << 9);
    float2 X0[8], X1[8];
#pragma unroll
    for (int q = 0; q < 8; ++q) {
        X0[q] = make_float2(xr[b0 + J + 64*q], yr[b0 + J + 64*q]);
        X1[q] = make_float2(xr[b1 + J + 64*q], yr[b1 + J + 64*q]);
    }
    __syncthreads();                       // T ready

    float2* Sw = S + w * 576;
    wave_fft512_dual(X0, X1, Sw, T, J);

    const int r = ((J & 7) << 3) | (J >> 3);

#pragma unroll
    for (int k = 0; k < 8; ++k) Sw[64*k + r] = X0[k];
    __syncthreads();
    float2 eA[4], eB[4];
#pragma unroll
    for (int j = 0; j < 4; ++j) { eA[j] = S[j*576 + t]; eB[j] = S[j*576 + t + 256]; }
    __syncthreads();

#pragma unroll
    for (int k = 0; k < 8; ++k) Sw[64*k + r] = X1[k];
    __syncthreads();

    // New layout store: thread t writes (kx=t, yin=0..7) = 8 consecutive
    // float2 at im<<18 | grp<<12 | t<<3. yin 0..3 = rows grp*8+{0..3} (X0
    // round, wave j), yin 4..7 = rows grp*8+{4..7} (X1 round, wave j).
    const size_t zb = ((size_t)im << 18) + ((size_t)grp << 12);
    {
        float4* o = (float4*)(Zt + zb + ((size_t)t << 3));
        float2 f0 = S[0*576 + t], f1 = S[1*576 + t];
        float2 f2 = S[2*576 + t], f3 = S[3*576 + t];
        o[0] = make_float4(eA[0].x, eA[0].y, eA[1].x, eA[1].y);
        o[1] = make_float4(eA[2].x, eA[2].y, eA[3].x, eA[3].y);
        o[2] = make_float4(f0.x, f0.y, f1.x, f1.y);
        o[3] = make_float4(f2.x, f2.y, f3.x, f3.y);
    }
    {
        float4* o = (float4*)(Zt + zb + ((size_t)(t + 256) << 3));
        float2 f0 = S[0*576 + t + 256], f1 = S[1*576 + t + 256];
        float2 f2 = S[2*576 + t + 256], f3 = S[3*576 + t + 256];
        o[0] = make_float4(eB[0].x, eB[0].y, eB[1].x, eB[1].y);
        o[1] = make_float4(eB[2].x, eB[2].y, eB[3].x, eB[3].y);
        o[2] = make_float4(f0.x, f0.y, f1.x, f1.y);
        o[3] = make_float4(f2.x, f2.y, f3.x, f3.y);
    }
}

// ---------------------------------------------------------------------------
// Fused column FFT + rings, v6:
//  - reads the [im][ygrp][kx][yin] layout (yin = J&7 is constant per lane)
//  - Hermitian pix-halving: for real inputs F(-k)=conj(F(k)) makes a,c1,c2
//    identical at mirror pixels, so compute one pix() and double it
//  - 8 shared slices/image via global atomics (NO private-slice big path)
//  - LAST BLOCK (device-scope counter, threadfence — standard last-block
//    reduce pattern) performs the former finalize kernel's work and writes
//    d_out directly. Kills the finalize launch + both memset nodes.
// ---------------------------------------------------------------------------
__global__ __launch_bounds__(256) void fft_cols_rings(const float2* __restrict__ Zt,
                                                      float* __restrict__ sums,
                                                      unsigned int* __restrict__ counter,
                                                      float* __restrict__ out) {
    __shared__ float2 S[4 * 576];      // 18,432 B
    __shared__ float2 T[576];          //  4,608 B
    __shared__ float  bins[258 * 3];   //  3,096 B
    __shared__ int    lastFlag;
    const int t = threadIdx.x, w = t >> 6, J = t & 63;
    const int im = blockIdx.x >> 6, g = blockIdx.x & 63;
    const int p = 4 * g + w;

#pragma unroll
    for (int i = 0; i < 2; ++i) {
        const int m = t + 256 * i;
        float s, c;
        __sincosf(-2.0f * PI_F * (float)m / 512.0f, &s, &c);
        T[m + (m >> 3)] = make_float2(c, s);
    }
    for (int i = t; i < 258 * 3; i += 256) bins[i] = 0.0f;

    const int c0 = (p == 0) ? 0   : p;
    const int c1 = (p == 0) ? 256 : 512 - p;
    // New-layout column gather: y = J + 64q -> yin = J&7 (lane-constant),
    // ygrp = (J>>3) + 8q. Each wave-load = 8 segments x 64 B.
    const size_t ibase = (size_t)im << 18;
    const int lane8 = J & 7, hi8 = J >> 3;
    const float2* q0 = Zt + ibase + ((size_t)c0 << 3) + lane8;
    const float2* q1 = Zt + ibase + ((size_t)c1 << 3) + lane8;
    float2 X0[8], X1[8];
#pragma unroll
    for (int q = 0; q < 8; ++q) {
        const size_t off = (size_t)(hi8 + 8*q) << 12;
        X0[q] = q0[off];
        X1[q] = q1[off];
    }
    __syncthreads();                       // T ready, bins zeroed

    float2* A = S + w * 576;               // single wave-private region
    const int r  = ((J & 7) << 3) | (J >> 3);
    const int pk = r + (r >> 3);           // sw(64k + r) = 72k + pk

    const float scale = 1.0f / (512.0f * 512.0f);
    auto pix = [&](float2 zk, float2 zm, float& av, float& c1v, float& c2v) {
        float f1r = 0.5f * (zk.x + zm.x) * scale;
        float f1i = 0.5f * (zk.y - zm.y) * scale;
        float f2r = 0.5f * (zk.y + zm.y) * scale;
        float f2i = 0.5f * (zm.x - zk.x) * scale;
        av  = f1r * f2r + f1i * f2i;
        c1v = f1r * f1r + f1i * f1i;
        c2v = f2r * f2r + f2i * f2i;
    };
    auto flush = [&](int ring, float a, float b, float c) {
        if (ring >= 0 && ring <= 256) {
            unsafeAtomicAdd(&bins[ring*3+0], a);
            unsafeAtomicAdd(&bins[ring*3+1], b);
            unsafeAtomicAdd(&bins[ring*3+2], c);
        }
    };

    wave_fft512_dual(X0, X1, A, T, J);

#pragma unroll
    for (int k = 0; k < 8; ++k) A[72*k + pk] = X0[k];

    float2 asv[8];
    if (p == 0) {
        int cur0 = -1;
        float a0 = 0, b0 = 0, c0v = 0;
#pragma unroll
        for (int i = 0; i < 8; ++i) {
            const int ky  = 8*J + i;
            const int kyp = (512 - ky) & 511;
            float2 zk = A[sw(ky)], zm = A[sw(kyp)];
            const float fk = (ky < 256) ? (float)ky : (float)(ky - 512);
            float av, cv, dv;
            pix(zk, zm, av, cv, dv);                       // col 0, fy = 0
            int rr = (int)rintf(fabsf(fk)); if (rr > 256) rr = 257;
            if (rr != cur0) { flush(cur0, a0, b0, c0v); cur0 = rr; a0 = av; b0 = cv; c0v = dv; }
            else            { a0 += av; b0 += cv; c0v += dv; }
        }
        flush(cur0, a0, b0, c0v);
    } else {
#pragma unroll
        for (int i = 0; i < 8; ++i) asv[i] = A[9*J + i];
    }

#pragma unroll
    for (int k = 0; k < 8; ++k) A[72*k + pk] = X1[k];

    if (p == 0) {
        int cur1 = -1;
        float a1 = 0, b1 = 0, c1v = 0;
#pragma unroll
        for (int i = 0; i < 8; ++i) {
            const int ky  = 8*J + i;
            const int kyp = (512 - ky) & 511;
            float2 zk = A[sw(ky)], zm = A[sw(kyp)];
            const float fk = (ky < 256) ? (float)ky : (float)(ky - 512);
            float av, cv, dv;
            pix(zk, zm, av, cv, dv);                       // col 256, fy = 256
            int rr = (int)rintf(sqrtf(fk*fk + 65536.0f)); if (rr > 256) rr = 257;
            if (rr != cur1) { flush(cur1, a1, b1, c1v); cur1 = rr; a1 = av; b1 = cv; c1v = dv; }
            else            { a1 += av; b1 += cv; c1v += dv; }
        }
        flush(cur1, a1, b1, c1v);
    } else {
        const float fy2 = (float)p * (float)p;
        int curR = -1;
        float sA = 0, sB = 0, sC = 0;
#pragma unroll
        for (int i = 0; i < 8; ++i) {
            const int ky  = 8*J + i;
            const int kyp = (512 - ky) & 511;
            float2 zk = asv[i];              // P0[ky]
            float2 zm = A[sw(kyp)];          // P1[512-ky]
            float a1v, b1v, d1v;
            pix(zk, zm, a1v, b1v, d1v);
            // Hermitian: mirror pixel (512-p, 512-ky) has identical a,c1,c2.
            const float fk = (ky < 256) ? (float)ky : (float)(ky - 512);
            int rr = (int)rintf(sqrtf(fk*fk + fy2)); if (rr > 256) rr = 257;
            const float aa = 2.0f*a1v, bb = 2.0f*b1v, cc = 2.0f*d1v;
            if (rr != curR) { flush(curR, sA, sB, sC); curR = rr; sA = aa; sB = bb; sC = cc; }
            else            { sA += aa; sB += bb; sC += cc; }
        }
        flush(curR, sA, sB, sC);
    }
    __syncthreads();

    // 8 shared slices per image, device-scope atomics
    {
        float* dst = sums + (size_t)(im * 8 + (g & 7)) * NB3;
        for (int i = t; i < NB3; i += 256) unsafeAtomicAdd(&dst[i], bins[i]);
    }

    // ---- last-block finalize (replaces the finalize kernel + d_out memset)
    __syncthreads();                       // drains this block's atomics (vmcnt 0)
    if (t == 0) {
        __threadfence();
        unsigned int old = atomicAdd(counter, 1u);
        lastFlag = (old == (unsigned int)(gridDim.x - 1)) ? 1 : 0;
    }
    __syncthreads();
    if (lastFlag) {
        __threadfence();                   // acquire: all blocks' sums visible
        float acc = 0.0f;
        for (int idx = t; idx < NIMG * 257; idx += 256) {
            const int imQ = idx / 257;
            const int rr  = idx - imQ * 257;
            const float* pp = sums + (size_t)imQ * 8 * NB3 + rr * 3;
            float cr = 0.f, c1s = 0.f, c2s = 0.f;
#pragma unroll
            for (int s = 0; s < 8; ++s) {
                cr  += pp[(size_t)s * NB3 + 0];
                c1s += pp[(size_t)s * NB3 + 1];
                c2s += pp[(size_t)s * NB3 + 2];
            }
            float frc = fabsf(cr) / (sqrtf(c1s * c2s) + 1e-8f);
            float d = 1.0f - frc;
            acc += d * d;
        }
#pragma unroll
        for (int off = 32; off > 0; off >>= 1) acc += __shfl_down(acc, off);
        __shared__ float red[4];
        if ((t & 63) == 0) red[t >> 6] = acc;
        __syncthreads();
        if (t == 0)
            out[0] = (red[0] + red[1] + red[2] + red[3]) *
                     (1.0f / (257.0f * (float)NIMG));
    }
}

// ---------------------------------------------------------------------------
extern "C" void kernel_launch(void* const* d_in, const int* in_sizes, int n_in,
                              void* d_out, int out_size, void* d_ws, size_t ws_size,
                              hipStream_t stream) {
    const float* xr = (const float*)d_in[0];   // output: 32x1x512x512 f32
    const float* yr = (const float*)d_in[1];   // target: 32x1x512x512 f32

    float2* Zt = (float2*)d_ws;                                    // 64 MiB
    const size_t ztBytes = ((size_t)NIMG << 18) * sizeof(float2);
    float* sums = (float*)((char*)d_ws + ztBytes);                 // 256*771 f32
    unsigned int* counter = (unsigned int*)((char*)d_ws + ztBytes +
                              (size_t)NSLICE * NB3 * sizeof(float));

    // 2 nodes total: sums zero + counter reset live in rows; finalize + d_out
    // write live in the last cols block.
    fft_rows_T    <<<dim3(NIMG * 64), dim3(256), 0, stream>>>(xr, yr, Zt, sums, counter);
    fft_cols_rings<<<dim3(NIMG * 64), dim3(256), 0, stream>>>(Zt, sums, counter, (float*)d_out);
}

// Round 5
// 196.288 us; speedup vs baseline: 1.0933x; 1.0295x over previous
//
#include <hip/hip_runtime.h>
#include <math.h>

#define NIMG 32
#define NB3  771             // 257 rings * 3 sums
#define NSLICE (NIMG * 8)    // 8 shared slices per image, global-atomic accumulated
#define PI_F 3.14159265358979323846f

// ---------------------------------------------------------------------------
__device__ __forceinline__ float2 cadd(float2 a, float2 b){ return make_float2(a.x+b.x, a.y+b.y); }
__device__ __forceinline__ float2 csub(float2 a, float2 b){ return make_float2(a.x-b.x, a.y-b.y); }
__device__ __forceinline__ float2 cmul(float2 a, float2 b){ return make_float2(a.x*b.x - a.y*b.y, a.x*b.y + a.y*b.x); }
__device__ __forceinline__ float2 cmul_mi(float2 a){ return make_float2(a.y, -a.x); }   // * (-i)
__device__ __forceinline__ float2 tw(const float2* T, int m){ return T[m + (m >> 3)]; }
__device__ __forceinline__ int   sw(int pos){ return pos + (pos >> 3); }     // LDS pad swizzle

// 8-point DFT (DIF, natural-order outputs), e^{-2pi i/8} convention
__device__ __forceinline__ void dft8(float2* x) {
    const float c = 0.70710678118654752f;
    float2 u0 = cadd(x[0], x[4]), u1 = cadd(x[1], x[5]);
    float2 u2 = cadd(x[2], x[6]), u3 = cadd(x[3], x[7]);
    float2 v0 = csub(x[0], x[4]);
    float2 d1 = csub(x[1], x[5]);
    float2 v1 = make_float2(c*(d1.x + d1.y), c*(d1.y - d1.x));
    float2 d2 = csub(x[2], x[6]);
    float2 v2 = make_float2(d2.y, -d2.x);
    float2 d3 = csub(x[3], x[7]);
    float2 v3 = make_float2(-c*(d3.x - d3.y), -c*(d3.x + d3.y));
    float2 e0 = cadd(u0,u2), e1 = cadd(u1,u3);
    float2 f0 = csub(u0,u2), f1 = cmul_mi(csub(u1,u3));
    float2 g0 = cadd(v0,v2), g1 = cadd(v1,v3);
    float2 h0 = csub(v0,v2), h1 = cmul_mi(csub(v1,v3));
    x[0] = cadd(e0,e1); x[4] = csub(e0,e1);
    x[2] = cadd(f0,f1); x[6] = csub(f0,f1);
    x[1] = cadd(g0,g1); x[5] = csub(g0,g1);
    x[3] = cadd(h0,h1); x[7] = csub(h0,h1);
}

// ---------------------------------------------------------------------------
// DUAL per-wave 512-pt radix-8 DIF FFT: two independent chains interleaved,
// sharing one 576-slot wave-private scratch (in-order LDS pipe makes the
// readA-before-writeB overlap safe). Thread J enters with X[q] = x[J+64q],
// exits with X[k] = F(64k + r), r = 8*(J&7) + (J>>3).
// ---------------------------------------------------------------------------
__device__ __forceinline__ void wave_fft512_dual(float2* Xa, float2* Xb,
                                                 float2* Sw, const float2* T,
                                                 int J) {
    dft8(Xa);
    dft8(Xb);
#pragma unroll
    for (int k = 1; k < 8; ++k) Xa[k] = cmul(Xa[k], tw(T, J * k));
#pragma unroll
    for (int k = 1; k < 8; ++k) Xb[k] = cmul(Xb[k], tw(T, J * k));
    const int jj = J + (J >> 3);
    const int j2 = J & 7;
    const int bb = 72 * (J >> 3) + j2;

#pragma unroll
    for (int k = 0; k < 8; ++k) Sw[jj + 72*k] = Xa[k];
#pragma unroll
    for (int q = 0; q < 8; ++q) Xa[q] = Sw[bb + 9*q];
#pragma unroll
    for (int k = 0; k < 8; ++k) Sw[jj + 72*k] = Xb[k];
#pragma unroll
    for (int q = 0; q < 8; ++q) Xb[q] = Sw[bb + 9*q];

    dft8(Xa);
    dft8(Xb);
#pragma unroll
    for (int k = 1; k < 8; ++k) Xa[k] = cmul(Xa[k], tw(T, 8 * j2 * k));
#pragma unroll
    for (int k = 1; k < 8; ++k) Xb[k] = cmul(Xb[k], tw(T, 8 * j2 * k));

#pragma unroll
    for (int k = 0; k < 8; ++k) Sw[bb + 9*k] = Xa[k];
#pragma unroll
    for (int q = 0; q < 8; ++q) Xa[q] = Sw[9*J + q];
#pragma unroll
    for (int k = 0; k < 8; ++k) Sw[bb + 9*k] = Xb[k];
#pragma unroll
    for (int q = 0; q < 8; ++q) Xb[q] = Sw[9*J + q];

    dft8(Xa);
    dft8(Xb);
}

// ---------------------------------------------------------------------------
// Row pass, r5: 512 threads / 16 image-rows per block, storing the OLD
// column-major layout Zt[im][kx][y] (cols reads are then fully contiguous —
// proven 73 µs in r3). The transpose scatter is eaten on the STORE side at
// FULL-LINE granularity: after the LDS park, thread t holds 16 y-values for
// kx = t and stores ONE contiguous 128 B line (8x float4). r0-r3's version
// stored 64 B granules (half-lines, partial-line RMW at HBM); r4's layout
// moved the scatter to cols' LOAD side at 64 B granules (FETCH +26%, cols
// 73->117 µs). 128 B store granules leave both sides full-line.
// Blocks 0..255 also zero one sums slice each; block 0 resets the counter
// (visible to cols via kernel-boundary flush).
// ---------------------------------------------------------------------------
__global__ __launch_bounds__(512) void fft_rows_T(const float* __restrict__ xr,
                                                  const float* __restrict__ yr,
                                                  float2* __restrict__ Zt,
                                                  float* __restrict__ sums,
                                                  unsigned int* __restrict__ counter) {
    __shared__ float2 S[8 * 576];      // 36,864 B (wave scratch + park)
    __shared__ float2 T[576];          //  4,608 B
    const int t = threadIdx.x, w = t >> 6, J = t & 63;
    const int im = blockIdx.x >> 5, grp = blockIdx.x & 31;   // 32 imgs x 32 grps

    if (blockIdx.x < NSLICE) {
        float* z = sums + (size_t)blockIdx.x * NB3;
        for (int i = t; i < NB3; i += 512) z[i] = 0.0f;
        if (blockIdx.x == 0 && t == 0) *counter = 0u;
    }

    {
        float s, c;
        __sincosf(-2.0f * PI_F * (float)t / 512.0f, &s, &c);
        T[t + (t >> 3)] = make_float2(c, s);
    }

    // wave w: rowA = grp*16 + w, rowB = grp*16 + 8 + w
    const size_t b0 = ((size_t)(im * 512 + grp * 16 + w)) << 9;
    const size_t b1 = b0 + ((size_t)8 << 9);
    float2 X0[8], X1[8];
#pragma unroll
    for (int q = 0; q < 8; ++q) {
        X0[q] = make_float2(xr[b0 + J + 64*q], yr[b0 + J + 64*q]);
        X1[q] = make_float2(xr[b1 + J + 64*q], yr[b1 + J + 64*q]);
    }
    __syncthreads();                       // T ready

    float2* Sw = S + w * 576;
    wave_fft512_dual(X0, X1, Sw, T, J);

    const int r = ((J & 7) << 3) | (J >> 3);

    // park X0 (rows y0..y0+7, one per wave) -> gather 8 y's per kx
#pragma unroll
    for (int k = 0; k < 8; ++k) Sw[64*k + r] = X0[k];
    __syncthreads();
    float2 eA[8];
#pragma unroll
    for (int j = 0; j < 8; ++j) eA[j] = S[j*576 + t];   // F_row(y0+j)(kx=t)
    __syncthreads();

    // park X1 (rows y0+8..y0+15)
#pragma unroll
    for (int k = 0; k < 8; ++k) Sw[64*k + r] = X1[k];
    __syncthreads();
    float2 eB[8];
#pragma unroll
    for (int j = 0; j < 8; ++j) eB[j] = S[j*576 + t];   // F_row(y0+8+j)(kx=t)

    // one full 128 B line per thread: Zt[im][t][grp*16 .. grp*16+15]
    float4* o = (float4*)(Zt + ((size_t)im << 18) + ((size_t)t << 9)
                             + (size_t)(grp * 16));
    o[0] = make_float4(eA[0].x, eA[0].y, eA[1].x, eA[1].y);
    o[1] = make_float4(eA[2].x, eA[2].y, eA[3].x, eA[3].y);
    o[2] = make_float4(eA[4].x, eA[4].y, eA[5].x, eA[5].y);
    o[3] = make_float4(eA[6].x, eA[6].y, eA[7].x, eA[7].y);
    o[4] = make_float4(eB[0].x, eB[0].y, eB[1].x, eB[1].y);
    o[5] = make_float4(eB[2].x, eB[2].y, eB[3].x, eB[3].y);
    o[6] = make_float4(eB[4].x, eB[4].y, eB[5].x, eB[5].y);
    o[7] = make_float4(eB[6].x, eB[6].y, eB[7].x, eB[7].y);
}

// ---------------------------------------------------------------------------
// Fused column FFT + rings, v7 = r4's structure (Hermitian pix-halving,
// 8 atomic slices/image, last-block finalize) with the LOAD side reverted to
// the r3-proven fully-contiguous column read (old Zt[im][kx][y] layout:
// 512 B contiguous per wave-load instruction).
// ---------------------------------------------------------------------------
__global__ __launch_bounds__(256) void fft_cols_rings(const float2* __restrict__ Zt,
                                                      float* __restrict__ sums,
                                                      unsigned int* __restrict__ counter,
                                                      float* __restrict__ out) {
    __shared__ float2 S[4 * 576];      // 18,432 B
    __shared__ float2 T[576];          //  4,608 B
    __shared__ float  bins[258 * 3];   //  3,096 B
    __shared__ int    lastFlag;
    const int t = threadIdx.x, w = t >> 6, J = t & 63;
    const int im = blockIdx.x >> 6, g = blockIdx.x & 63;
    const int p = 4 * g + w;

#pragma unroll
    for (int i = 0; i < 2; ++i) {
        const int m = t + 256 * i;
        float s, c;
        __sincosf(-2.0f * PI_F * (float)m / 512.0f, &s, &c);
        T[m + (m >> 3)] = make_float2(c, s);
    }
    for (int i = t; i < 258 * 3; i += 256) bins[i] = 0.0f;

    const int c0 = (p == 0) ? 0   : p;
    const int c1 = (p == 0) ? 256 : 512 - p;
    const float2* rp0 = Zt + ((size_t)im << 18) + ((size_t)c0 << 9);
    const float2* rp1 = Zt + ((size_t)im << 18) + ((size_t)c1 << 9);
    float2 X0[8], X1[8];
#pragma unroll
    for (int q = 0; q < 8; ++q) { X0[q] = rp0[J + 64*q]; X1[q] = rp1[J + 64*q]; }
    __syncthreads();                       // T ready, bins zeroed

    float2* A = S + w * 576;               // single wave-private region
    const int r  = ((J & 7) << 3) | (J >> 3);
    const int pk = r + (r >> 3);           // sw(64k + r) = 72k + pk

    const float scale = 1.0f / (512.0f * 512.0f);
    auto pix = [&](float2 zk, float2 zm, float& av, float& c1v, float& c2v) {
        float f1r = 0.5f * (zk.x + zm.x) * scale;
        float f1i = 0.5f * (zk.y - zm.y) * scale;
        float f2r = 0.5f * (zk.y + zm.y) * scale;
        float f2i = 0.5f * (zm.x - zk.x) * scale;
        av  = f1r * f2r + f1i * f2i;
        c1v = f1r * f1r + f1i * f1i;
        c2v = f2r * f2r + f2i * f2i;
    };
    auto flush = [&](int ring, float a, float b, float c) {
        if (ring >= 0 && ring <= 256) {
            unsafeAtomicAdd(&bins[ring*3+0], a);
            unsafeAtomicAdd(&bins[ring*3+1], b);
            unsafeAtomicAdd(&bins[ring*3+2], c);
        }
    };

    wave_fft512_dual(X0, X1, A, T, J);

#pragma unroll
    for (int k = 0; k < 8; ++k) A[72*k + pk] = X0[k];

    float2 asv[8];
    if (p == 0) {
        int cur0 = -1;
        float a0 = 0, b0 = 0, c0v = 0;
#pragma unroll
        for (int i = 0; i < 8; ++i) {
            const int ky  = 8*J + i;
            const int kyp = (512 - ky) & 511;
            float2 zk = A[sw(ky)], zm = A[sw(kyp)];
            const float fk = (ky < 256) ? (float)ky : (float)(ky - 512);
            float av, cv, dv;
            pix(zk, zm, av, cv, dv);                       // col 0, fy = 0
            int rr = (int)rintf(fabsf(fk)); if (rr > 256) rr = 257;
            if (rr != cur0) { flush(cur0, a0, b0, c0v); cur0 = rr; a0 = av; b0 = cv; c0v = dv; }
            else            { a0 += av; b0 += cv; c0v += dv; }
        }
        flush(cur0, a0, b0, c0v);
    } else {
#pragma unroll
        for (int i = 0; i < 8; ++i) asv[i] = A[9*J + i];
    }

#pragma unroll
    for (int k = 0; k < 8; ++k) A[72*k + pk] = X1[k];

    if (p == 0) {
        int cur1 = -1;
        float a1 = 0, b1 = 0, c1v = 0;
#pragma unroll
        for (int i = 0; i < 8; ++i) {
            const int ky  = 8*J + i;
            const int kyp = (512 - ky) & 511;
            float2 zk = A[sw(ky)], zm = A[sw(kyp)];
            const float fk = (ky < 256) ? (float)ky : (float)(ky - 512);
            float av, cv, dv;
            pix(zk, zm, av, cv, dv);                       // col 256, fy = 256
            int rr = (int)rintf(sqrtf(fk*fk + 65536.0f)); if (rr > 256) rr = 257;
            if (rr != cur1) { flush(cur1, a1, b1, c1v); cur1 = rr; a1 = av; b1 = cv; c1v = dv; }
            else            { a1 += av; b1 += cv; c1v += dv; }
        }
        flush(cur1, a1, b1, c1v);
    } else {
        const float fy2 = (float)p * (float)p;
        int curR = -1;
        float sA = 0, sB = 0, sC = 0;
#pragma unroll
        for (int i = 0; i < 8; ++i) {
            const int ky  = 8*J + i;
            const int kyp = (512 - ky) & 511;
            float2 zk = asv[i];              // P0[ky]
            float2 zm = A[sw(kyp)];          // P1[512-ky]
            float a1v, b1v, d1v;
            pix(zk, zm, a1v, b1v, d1v);
            // Hermitian: mirror pixel (512-p, 512-ky) has identical a,c1,c2.
            const float fk = (ky < 256) ? (float)ky : (float)(ky - 512);
            int rr = (int)rintf(sqrtf(fk*fk + fy2)); if (rr > 256) rr = 257;
            const float aa = 2.0f*a1v, bb = 2.0f*b1v, cc = 2.0f*d1v;
            if (rr != curR) { flush(curR, sA, sB, sC); curR = rr; sA = aa; sB = bb; sC = cc; }
            else            { sA += aa; sB += bb; sC += cc; }
        }
        flush(curR, sA, sB, sC);
    }
    __syncthreads();

    // 8 shared slices per image, device-scope atomics
    {
        float* dst = sums + (size_t)(im * 8 + (g & 7)) * NB3;
        for (int i = t; i < NB3; i += 256) unsafeAtomicAdd(&dst[i], bins[i]);
    }

    // ---- last-block finalize (replaces the finalize kernel + d_out memset)
    __syncthreads();
    if (t == 0) {
        __threadfence();
        unsigned int old = atomicAdd(counter, 1u);
        lastFlag = (old == (unsigned int)(gridDim.x - 1)) ? 1 : 0;
    }
    __syncthreads();
    if (lastFlag) {
        __threadfence();                   // acquire: all blocks' sums visible
        float acc = 0.0f;
        for (int idx = t; idx < NIMG * 257; idx += 256) {
            const int imQ = idx / 257;
            const int rr  = idx - imQ * 257;
            const float* pp = sums + (size_t)imQ * 8 * NB3 + rr * 3;
            float cr = 0.f, c1s = 0.f, c2s = 0.f;
#pragma unroll
            for (int s = 0; s < 8; ++s) {
                cr  += pp[(size_t)s * NB3 + 0];
                c1s += pp[(size_t)s * NB3 + 1];
                c2s += pp[(size_t)s * NB3 + 2];
            }
            float frc = fabsf(cr) / (sqrtf(c1s * c2s) + 1e-8f);
            float d = 1.0f - frc;
            acc += d * d;
        }
#pragma unroll
        for (int off = 32; off > 0; off >>= 1) acc += __shfl_down(acc, off);
        __shared__ float red[4];
        if ((t & 63) == 0) red[t >> 6] = acc;
        __syncthreads();
        if (t == 0)
            out[0] = (red[0] + red[1] + red[2] + red[3]) *
                     (1.0f / (257.0f * (float)NIMG));
    }
}

// ---------------------------------------------------------------------------
extern "C" void kernel_launch(void* const* d_in, const int* in_sizes, int n_in,
                              void* d_out, int out_size, void* d_ws, size_t ws_size,
                              hipStream_t stream) {
    const float* xr = (const float*)d_in[0];   // output: 32x1x512x512 f32
    const float* yr = (const float*)d_in[1];   // target: 32x1x512x512 f32

    float2* Zt = (float2*)d_ws;                                    // 64 MiB
    const size_t ztBytes = ((size_t)NIMG << 18) * sizeof(float2);
    float* sums = (float*)((char*)d_ws + ztBytes);                 // 256*771 f32
    unsigned int* counter = (unsigned int*)((char*)d_ws + ztBytes +
                              (size_t)NSLICE * NB3 * sizeof(float));

    // 2 nodes: sums zero + counter reset live in rows; finalize + d_out
    // write live in the last cols block.
    fft_rows_T    <<<dim3(NIMG * 32), dim3(512), 0, stream>>>(xr, yr, Zt, sums, counter);
    fft_cols_rings<<<dim3(NIMG * 64), dim3(256), 0, stream>>>(Zt, sums, counter, (float*)d_out);
}